// Round 10
// baseline (143.166 us; speedup 1.0000x reference)
//
#include <hip/hip_runtime.h>
#include <math.h>

#define DK 32
#define OUT_DIM 32

typedef float    f32x4 __attribute__((ext_vector_type(4)));
typedef _Float16 h2    __attribute__((ext_vector_type(2)));
typedef _Float16 h8    __attribute__((ext_vector_type(8)));

#if __has_builtin(__builtin_amdgcn_fdot2)
#define FDOT2(a, b, c) __builtin_amdgcn_fdot2((a), (b), (c), false)
#else
#define FDOT2(a, b, c) ((c) + (float)(a).x * (float)(b).x + (float)(a).y * (float)(b).y)
#endif

__device__ __forceinline__ h2 as_h2(unsigned u) {
    union { unsigned u; h2 h; } v; v.u = u; return v.h;
}
__device__ __forceinline__ unsigned as_u32(h2 h) {
    union { unsigned u; h2 h; } v; v.h = h; return v.u;
}
__device__ __forceinline__ h2 shfl_xor_h2(h2 v, int m) {
    union { unsigned u; h2 h; } x; x.h = v;
    x.u = (unsigned)__shfl_xor((int)x.u, m);
    return x.h;
}

// Fused prep: (a) row_ptr[n] = first edge with dst >= n (boundary detect on
// sorted dst); (b) KVH: per node row of 32 dwords, chunk c (dims 4c..4c+3)
// = {f16(K[4c],K[4c+1]), f16(K[4c+2],K[4c+3]), f16(V...), f16(V...)} so one
// 128 B row still carries both K and V, now as f16 pairs ready for
// v_dot2_f32_f16 / v_pk_fma_f16.
__global__ void prep_kernel(const int* __restrict__ dst,
                            const float* __restrict__ K,
                            const float* __restrict__ V,
                            int E, int N,
                            int* __restrict__ row_ptr,
                            unsigned* __restrict__ KVH) {
    const int t = blockIdx.x * blockDim.x + threadIdx.x;
    if (t < E) {
        const int cur  = dst[t];
        const int prev = (t == 0) ? -1 : dst[t - 1];
        for (int j = prev + 1; j <= cur; ++j) row_ptr[j] = t;
        if (t == E - 1) {
            for (int j = cur + 1; j <= N; ++j) row_ptr[j] = E;
        }
    }
    if (t < N * DK) {
        const int s = t >> 5;          // node
        const int r = t & 31;          // dword within row
        const int c = r >> 2;          // chunk
        const int q = r & 3;           // 0:K01 1:K23 2:V01 3:V23
        const float* srcp = (q < 2) ? K : V;
        const int d0 = c * 4 + (q & 1) * 2;
        h2 h;
        h.x = (_Float16)srcp[s * DK + d0];
        h.y = (_Float16)srcp[s * DK + d0 + 1];
        KVH[t] = as_u32(h);
    }
}

// Fallback-path row_ptr builder (ws too small for KV).
__global__ void build_row_ptr_kernel(const int* __restrict__ dst, int E, int N,
                                     int* __restrict__ row_ptr) {
    int e = blockIdx.x * blockDim.x + threadIdx.x;
    if (e >= E) return;
    int cur  = dst[e];
    int prev = (e == 0) ? -1 : dst[e - 1];
    for (int j = prev + 1; j <= cur; ++j) row_ptr[j] = e;
    if (e == E - 1) {
        for (int j = cur + 1; j <= N; ++j) row_ptr[j] = E;
    }
}

// R10 = R9 partition (block = 4 waves = 16 nodes, 4 nodes per wave, grid
// 6250 blocks -> ~24 blocks/CU for TLP latency hiding) with an f16 VALU
// diet: dot = v_dot2_f32_f16 (f32 accum), V-accumulate = v_pk_fma_f16 on
// half2 acc regs, epilogue pk-ops, MFMA f16. One 128 B KV line per edge
// gather unchanged. No running max (scores ~ N(0,1/32), exp safe).
// Epilogue: per node xor(8) merge -> 4 partials, normalize, store half2s to
// the block A-tile; one barrier; wave 0 folds partial-reduction + W_o
// projection for all 16 nodes with 8 f16 MFMAs:
//   out(16x32) = part(16x[4x32]) @ Wrep([4x32]x32) + b.
__global__ __launch_bounds__(256) void gat_fused_kernel(
    const float* __restrict__ X, const uint4* __restrict__ KV,
    const float* __restrict__ Wo, const float* __restrict__ bo,
    const int* __restrict__ src, const int* __restrict__ row_ptr,
    float* __restrict__ out, int N) {

    __shared__ uint4 s_part[16 * 17];   // block A-tile, row stride 17 (pad->b128)

    const int tid  = threadIdx.x;
    const int w    = tid >> 6;    // wave 0..3
    const int lane = tid & 63;
    const int g    = lane >> 3;   // edge slot 0..7
    const int c    = lane & 7;    // dim chunk 0..7

    const int n_blk = blockIdx.x * 16;       // block's first node (< N always)
    const int n_w   = n_blk + w * 4;         // wave's first node

    // row_ptr[n_w .. n_w+4] into lanes 0..4 (clamped; row_ptr[N] = E)
    const int rpv = row_ptr[min(n_w + min(lane, 4), N)];

    const float4* X4 = (const float4*)X;
    unsigned* part32 = (unsigned*)s_part;
    const float scale = 0.03125f;

    for (int i = 0; i < 4; ++i) {
        const int begin = __builtin_amdgcn_readlane(rpv, i);
        const int end   = __builtin_amdgcn_readlane(rpv, i + 1);
        const int n     = n_w + i;           // may be >= N in last block

        float4 q = X4[min(n, N - 1) * 8 + c];
        h2 qh01, qh23;                       // scaled q as f16 pairs
        qh01.x = (_Float16)(q.x * scale);  qh01.y = (_Float16)(q.y * scale);
        qh23.x = (_Float16)(q.z * scale);  qh23.y = (_Float16)(q.w * scale);

        float l = 0.0f;
        h2 acc01 = (h2)0, acc23 = (h2)0;     // dims 4c..4c+3 accumulate (f16)

        for (int e0 = begin; e0 < end; e0 += 16) {
            const int sa = src[min(e0 + g,     end - 1)];
            const int sb = src[min(e0 + 8 + g, end - 1)];
            const uint4 A = KV[sa * 8 + c];   // 8 KV rows per wave load
            const uint4 B = KV[sb * 8 + c];

            // per-lane partial dot over 4 dims: 2 hardware dot2 each
            float p0 = FDOT2(as_h2(A.y), qh23, FDOT2(as_h2(A.x), qh01, 0.0f));
            float p1 = FDOT2(as_h2(B.y), qh23, FDOT2(as_h2(B.x), qh01, 0.0f));
            p0 += __shfl_xor(p0, 1);  p1 += __shfl_xor(p1, 1);
            p0 += __shfl_xor(p0, 2);  p1 += __shfl_xor(p1, 2);
            p0 += __shfl_xor(p0, 4);  p1 += __shfl_xor(p1, 4);

            const float w0 = (e0 + g     < end) ? __expf(p0) : 0.0f;
            const float w1 = (e0 + 8 + g < end) ? __expf(p1) : 0.0f;
            l += w0 + w1;

            h2 wh0; wh0.x = (_Float16)w0; wh0.y = wh0.x;
            h2 wh1; wh1.x = (_Float16)w1; wh1.y = wh1.x;
            acc01 += wh0 * as_h2(A.z);        // v_pk_fma_f16
            acc23 += wh0 * as_h2(A.w);
            acc01 += wh1 * as_h2(B.z);
            acc23 += wh1 * as_h2(B.w);
        }

        // 8 -> 4 partials (xor 8); l needs the full reduction
        l     += __shfl_xor(l, 8);
        acc01 += shfl_xor_h2(acc01, 8);
        acc23 += shfl_xor_h2(acc23, 8);
        l += __shfl_xor(l, 16);  l += __shfl_xor(l, 32);

        const float inv = (end > begin) ? (1.0f / l) : 0.0f;
        h2 invh; invh.x = (_Float16)inv; invh.y = invh.x;
        acc01 *= invh;
        acc23 *= invh;

        if ((g & 1) == 0) {                  // even groups hold pair sums
            const int p   = g >> 1;
            const int row = w * 4 + i;
            const int off = row * 68 + p * 16 + c * 2;   // uint32 units
            part32[off]     = as_u32(acc01);
            part32[off + 1] = as_u32(acc23);
        }
    }

    __syncthreads();

    // wave 0: projection + partial-group reduction for the block's 16 nodes
    if (w == 0) {
        const int quad = lane >> 4;   // 0..3
        const int col  = lane & 15;

        union BF { h8 v; _Float16 u[8]; };
        BF bf0, bf1;
#pragma unroll
        for (int j2 = 0; j2 < 8; ++j2) {
            bf0.u[j2] = (_Float16)Wo[(quad * 8 + j2) * OUT_DIM + col];
            bf1.u[j2] = (_Float16)Wo[(quad * 8 + j2) * OUT_DIM + 16 + col];
        }
        const float bias0 = bo[col];
        const float bias1 = bo[16 + col];

        union AF { uint4 u; h8 v; };
        f32x4 C0 = {bias0, bias0, bias0, bias0};
        f32x4 C1 = {bias1, bias1, bias1, bias1};
#pragma unroll
        for (int cc = 0; cc < 4; ++cc) {
            AF a;
            a.u = s_part[col * 17 + cc * 4 + quad];      // ds_read_b128
            C0 = __builtin_amdgcn_mfma_f32_16x16x32_f16(a.v, bf0.v, C0, 0, 0, 0);
            C1 = __builtin_amdgcn_mfma_f32_16x16x32_f16(a.v, bf1.v, C1, 0, 0, 0);
        }
        // C/D layout: col = lane&15, row = quad*4 + reg (verified mapping)
#pragma unroll
        for (int r = 0; r < 4; ++r) {
            const int n = n_blk + quad * 4 + r;
            if (n < N) {
                out[n * OUT_DIM + col]      = C0[r];
                out[n * OUT_DIM + 16 + col] = C1[r];
            }
        }
    }
}

// ---- fallback (R4-proven fp32 path, used only if ws too small for KV) ----
__global__ __launch_bounds__(256) void gat_node_f32_kernel(
    const float* __restrict__ X, const float* __restrict__ Km,
    const float* __restrict__ Vm, const float* __restrict__ Wo,
    const float* __restrict__ bo, const int* __restrict__ src,
    const int* __restrict__ row_ptr, float* __restrict__ out, int N) {
    const int tid  = threadIdx.x;
    const int wave = tid >> 6;
    const int lane = tid & 63;
    const int g    = lane >> 3;
    const int c    = lane & 7;
    const int j    = lane & 31;
    const int half = lane >> 5;
    const int n = blockIdx.x * 4 + wave;
    if (n >= N) return;
    const int begin = row_ptr[n];
    const int end   = row_ptr[n + 1];
    const float4* X4 = (const float4*)X;
    const float4* K4 = (const float4*)Km;
    const float4* V4 = (const float4*)Vm;
    const float4 q4 = X4[n * 8 + c];
    float  l   = 0.0f;
    float4 acc = make_float4(0.0f, 0.0f, 0.0f, 0.0f);
    for (int e0 = begin; e0 < end; e0 += 16) {
        const int  ea = e0 + g;
        const int  eb = ea + 8;
        const bool va = ea < end;
        const bool vb = eb < end;
        const int sa = src[min(ea, end - 1)];
        const int sb = src[min(eb, end - 1)];
        const float4 ka  = K4[sa * 8 + c];
        const float4 kb  = K4[sb * 8 + c];
        const float4 vva = V4[sa * 8 + c];
        const float4 vvb = V4[sb * 8 + c];
        float pa = fmaf(ka.x, q4.x, fmaf(ka.y, q4.y, fmaf(ka.z, q4.z, ka.w * q4.w)));
        float pb = fmaf(kb.x, q4.x, fmaf(kb.y, q4.y, fmaf(kb.z, q4.z, kb.w * q4.w)));
        pa += __shfl_xor(pa, 1);  pb += __shfl_xor(pb, 1);
        pa += __shfl_xor(pa, 2);  pb += __shfl_xor(pb, 2);
        pa += __shfl_xor(pa, 4);  pb += __shfl_xor(pb, 4);
        const float wa = va ? __expf(pa * 0.03125f) : 0.0f;
        const float wb = vb ? __expf(pb * 0.03125f) : 0.0f;
        l += wa + wb;
        acc.x = fmaf(wa, vva.x, acc.x);  acc.y = fmaf(wa, vva.y, acc.y);
        acc.z = fmaf(wa, vva.z, acc.z);  acc.w = fmaf(wa, vva.w, acc.w);
        acc.x = fmaf(wb, vvb.x, acc.x);  acc.y = fmaf(wb, vvb.y, acc.y);
        acc.z = fmaf(wb, vvb.z, acc.z);  acc.w = fmaf(wb, vvb.w, acc.w);
    }
#pragma unroll
    for (int m = 8; m <= 32; m <<= 1) {
        l     += __shfl_xor(l, m);
        acc.x += __shfl_xor(acc.x, m);
        acc.y += __shfl_xor(acc.y, m);
        acc.z += __shfl_xor(acc.z, m);
        acc.w += __shfl_xor(acc.w, m);
    }
    const float inv = (end > begin) ? (1.0f / l) : 0.0f;
    float ag[4] = {acc.x, acc.y, acc.z, acc.w};
    float s = 0.0f;
#pragma unroll
    for (int k = 0; k < 32; ++k) {
        const float a = __int_as_float(
            __builtin_amdgcn_readlane(__float_as_int(ag[k & 3]), k >> 2));
        s = fmaf(a, Wo[k * OUT_DIM + j], s);
    }
    if (half == 0) {
        out[n * OUT_DIM + j] = fmaf(s, inv, bo[j]);
    }
}

extern "C" void kernel_launch(void* const* d_in, const int* in_sizes, int n_in,
                              void* d_out, int out_size, void* d_ws, size_t ws_size,
                              hipStream_t stream) {
    const float* X  = (const float*)d_in[0];
    const float* Km = (const float*)d_in[1];
    const float* Vm = (const float*)d_in[2];
    const float* Wo = (const float*)d_in[3];
    const float* bo = (const float*)d_in[4];
    const int* src  = (const int*)d_in[5];
    const int* dst  = (const int*)d_in[6];

    const int N = in_sizes[0] / DK;
    const int E = in_sizes[5];

    int* row_ptr = (int*)d_ws;                              // (N+1) ints
    const size_t kv_off = (((size_t)(N + 1) * 4) + 127) & ~(size_t)127;
    unsigned* KV = (unsigned*)((char*)d_ws + kv_off);       // N*DK uint32
    const size_t need = kv_off + (size_t)N * DK * 4;
    float* out = (float*)d_out;

    const int tb = 256;

    if (ws_size >= need) {
        const int total  = N * DK;
        const int prep_n = (E > total) ? E : total;
        prep_kernel<<<(prep_n + tb - 1) / tb, tb, 0, stream>>>(dst, Km, Vm, E, N,
                                                               row_ptr, KV);
        const int grid = (N + 15) / 16;     // 16 nodes per block, 4 per wave
        gat_fused_kernel<<<grid, 256, 0, stream>>>(X, (const uint4*)KV, Wo, bo,
                                                   src, row_ptr, out, N);
    } else {
        build_row_ptr_kernel<<<(E + tb - 1) / tb, tb, 0, stream>>>(dst, E, N, row_ptr);
        const int grid = (N + 3) / 4;
        gat_node_f32_kernel<<<grid, 256, 0, stream>>>(X, Km, Vm, Wo, bo,
                                                      src, row_ptr, out, N);
    }
}

// Round 11
// 134.379 us; speedup vs baseline: 1.0654x; 1.0654x over previous
//
#include <hip/hip_runtime.h>
#include <math.h>

#define DK 32
#define OUT_DIM 32

typedef float    f32x4 __attribute__((ext_vector_type(4)));
typedef _Float16 h2    __attribute__((ext_vector_type(2)));
typedef _Float16 h8    __attribute__((ext_vector_type(8)));

#if __has_builtin(__builtin_amdgcn_fdot2)
#define FDOT2(a, b, c) __builtin_amdgcn_fdot2((a), (b), (c), false)
#else
#define FDOT2(a, b, c) ((c) + (float)(a).x * (float)(b).x + (float)(a).y * (float)(b).y)
#endif

__device__ __forceinline__ h2 as_h2(unsigned u) {
    union { unsigned u; h2 h; } v; v.u = u; return v.h;
}
__device__ __forceinline__ unsigned as_u32(h2 h) {
    union { unsigned u; h2 h; } v; v.h = h; return v.u;
}
__device__ __forceinline__ h2 shfl_xor_h2(h2 v, int m) {
    union { unsigned u; h2 h; } x; x.h = v;
    x.u = (unsigned)__shfl_xor((int)x.u, m);
    return x.h;
}

// Fused prep: (a) row_ptr[n] = first edge with dst >= n (boundary detect on
// sorted dst); (b) KVH: per node row of 32 dwords, chunk c (dims 4c..4c+3)
// = {f16(K[4c..4c+1]), f16(K[4c+2..3]), f16(V[4c..4c+1]), f16(V[4c+2..3])}
// so one 128 B row carries both K and V as f16 pairs ready for
// v_dot2_f32_f16 / v_pk_fma_f16.
__global__ void prep_kernel(const int* __restrict__ dst,
                            const float* __restrict__ K,
                            const float* __restrict__ V,
                            int E, int N,
                            int* __restrict__ row_ptr,
                            unsigned* __restrict__ KVH) {
    const int t = blockIdx.x * blockDim.x + threadIdx.x;
    if (t < E) {
        const int cur  = dst[t];
        const int prev = (t == 0) ? -1 : dst[t - 1];
        for (int j = prev + 1; j <= cur; ++j) row_ptr[j] = t;
        if (t == E - 1) {
            for (int j = cur + 1; j <= N; ++j) row_ptr[j] = E;
        }
    }
    if (t < N * DK) {
        const int s = t >> 5;          // node
        const int r = t & 31;          // dword within row
        const int c = r >> 2;          // chunk
        const int q = r & 3;           // 0:K01 1:K23 2:V01 3:V23
        const float* srcp = (q < 2) ? K : V;
        const int d0 = c * 4 + (q & 1) * 2;
        h2 h;
        h.x = (_Float16)srcp[s * DK + d0];
        h.y = (_Float16)srcp[s * DK + d0 + 1];
        KVH[t] = as_u32(h);
    }
}

// Fallback-path row_ptr builder (ws too small for KV).
__global__ void build_row_ptr_kernel(const int* __restrict__ dst, int E, int N,
                                     int* __restrict__ row_ptr) {
    int e = blockIdx.x * blockDim.x + threadIdx.x;
    if (e >= E) return;
    int cur  = dst[e];
    int prev = (e == 0) ? -1 : dst[e - 1];
    for (int j = prev + 1; j <= cur; ++j) row_ptr[j] = e;
    if (e == E - 1) {
        for (int j = cur + 1; j <= N; ++j) row_ptr[j] = E;
    }
}

// R11 = R9/R10 partition (block = 4 waves = 16 nodes, 4 nodes per wave,
// ~24 blocks/CU) + BRANCHLESS 2-node lockstep edge loop: each step issues
// node A's and node B's gathers together (4 src + 4 KV chains in flight,
// up from 2) and the per-wave serial batch count drops from
// 4*E[ceil(d/16)]=5.9 to 2*E[max(...)]=3.4. All loads unconditional with
// clamped indices (finished/empty segments re-read their last line -> L1
// hit, weight masked to 0 at the exp; R7's mistake was branching here).
// f16 math: dot = v_dot2_f32_f16, V-accum = v_pk_fma_f16 (R10-proven).
// Epilogue per node: xor(8) -> 4 partials, l-reduce, normalize, half2s to
// block A-tile; one barrier; wave 0 folds partial-reduction + projection
// for all 16 nodes with 8 f16 MFMAs:
//   out(16x32) = part(16x[4x32]) @ Wrep([4x32]x32) + b.
__global__ __launch_bounds__(256) void gat_fused_kernel(
    const float* __restrict__ X, const uint4* __restrict__ KV,
    const float* __restrict__ Wo, const float* __restrict__ bo,
    const int* __restrict__ src, const int* __restrict__ row_ptr,
    float* __restrict__ out, int N) {

    __shared__ uint4 s_part[16 * 17];   // block A-tile, row stride 17 (pad->b128)

    const int tid  = threadIdx.x;
    const int w    = tid >> 6;    // wave 0..3
    const int lane = tid & 63;
    const int g    = lane >> 3;   // edge slot 0..7
    const int c    = lane & 7;    // dim chunk 0..7

    const int n_blk = blockIdx.x * 16;       // block's first node (< N always)
    const int n_w   = n_blk + w * 4;         // wave's first node

    // row_ptr[n_w .. n_w+4] into lanes 0..4 (clamped; row_ptr[N] = E)
    const int rpv = row_ptr[min(n_w + min(lane, 4), N)];

    const float4* X4 = (const float4*)X;
    unsigned* part32 = (unsigned*)s_part;
    const float scale = 0.03125f;

    for (int pr = 0; pr < 2; ++pr) {
        const int ia = pr * 2;
        const int beginA = __builtin_amdgcn_readlane(rpv, ia);
        const int endA   = __builtin_amdgcn_readlane(rpv, ia + 1);
        const int endB   = __builtin_amdgcn_readlane(rpv, ia + 2);
        const int beginB = endA;
        const int nA = n_w + ia;             // may be >= N in last block
        const int nB = nA + 1;

        float4 qa = X4[min(nA, N - 1) * 8 + c];
        float4 qb = X4[min(nB, N - 1) * 8 + c];
        h2 qa01, qa23, qb01, qb23;           // scaled q as f16 pairs
        qa01.x = (_Float16)(qa.x * scale);  qa01.y = (_Float16)(qa.y * scale);
        qa23.x = (_Float16)(qa.z * scale);  qa23.y = (_Float16)(qa.w * scale);
        qb01.x = (_Float16)(qb.x * scale);  qb01.y = (_Float16)(qb.y * scale);
        qb23.x = (_Float16)(qb.z * scale);  qb23.y = (_Float16)(qb.w * scale);

        float lA = 0.0f, lB = 0.0f;
        h2 aA01 = (h2)0, aA23 = (h2)0, aB01 = (h2)0, aB23 = (h2)0;

        const int capA = max(endA - 1, 0);   // safe clamp (empty -> idx 0)
        const int capB = max(endB - 1, 0);
        int eA = beginA, eB = beginB;

        while (eA < endA || eB < endB) {     // scalar condition
            // ---- issue all 4 src + 4 KV chains, no branches ----
            const int sa0 = src[min(eA + g,     capA)];
            const int sa1 = src[min(eA + 8 + g, capA)];
            const int sb0 = src[min(eB + g,     capB)];
            const int sb1 = src[min(eB + 8 + g, capB)];
            const uint4 A0 = KV[sa0 * 8 + c];
            const uint4 A1 = KV[sa1 * 8 + c];
            const uint4 B0 = KV[sb0 * 8 + c];
            const uint4 B1 = KV[sb1 * 8 + c];

            float p0 = FDOT2(as_h2(A0.y), qa23, FDOT2(as_h2(A0.x), qa01, 0.0f));
            float p1 = FDOT2(as_h2(A1.y), qa23, FDOT2(as_h2(A1.x), qa01, 0.0f));
            float p2 = FDOT2(as_h2(B0.y), qb23, FDOT2(as_h2(B0.x), qb01, 0.0f));
            float p3 = FDOT2(as_h2(B1.y), qb23, FDOT2(as_h2(B1.x), qb01, 0.0f));
            p0 += __shfl_xor(p0, 1);  p1 += __shfl_xor(p1, 1);
            p2 += __shfl_xor(p2, 1);  p3 += __shfl_xor(p3, 1);
            p0 += __shfl_xor(p0, 2);  p1 += __shfl_xor(p1, 2);
            p2 += __shfl_xor(p2, 2);  p3 += __shfl_xor(p3, 2);
            p0 += __shfl_xor(p0, 4);  p1 += __shfl_xor(p1, 4);
            p2 += __shfl_xor(p2, 4);  p3 += __shfl_xor(p3, 4);

            const float w0 = (eA + g     < endA) ? __expf(p0) : 0.0f;
            const float w1 = (eA + 8 + g < endA) ? __expf(p1) : 0.0f;
            const float w2 = (eB + g     < endB) ? __expf(p2) : 0.0f;
            const float w3 = (eB + 8 + g < endB) ? __expf(p3) : 0.0f;
            lA += w0 + w1;
            lB += w2 + w3;

            h2 wh0; wh0.x = (_Float16)w0; wh0.y = wh0.x;
            h2 wh1; wh1.x = (_Float16)w1; wh1.y = wh1.x;
            h2 wh2; wh2.x = (_Float16)w2; wh2.y = wh2.x;
            h2 wh3; wh3.x = (_Float16)w3; wh3.y = wh3.x;
            aA01 += wh0 * as_h2(A0.z);  aA23 += wh0 * as_h2(A0.w);
            aA01 += wh1 * as_h2(A1.z);  aA23 += wh1 * as_h2(A1.w);
            aB01 += wh2 * as_h2(B0.z);  aB23 += wh2 * as_h2(B0.w);
            aB01 += wh3 * as_h2(B1.z);  aB23 += wh3 * as_h2(B1.w);

            eA += 16; eB += 16;
        }

        // ---- per-node reductions + A-tile writes (A then B) ----
        lA   += __shfl_xor(lA, 8);
        aA01 += shfl_xor_h2(aA01, 8);
        aA23 += shfl_xor_h2(aA23, 8);
        lA += __shfl_xor(lA, 16);  lA += __shfl_xor(lA, 32);

        lB   += __shfl_xor(lB, 8);
        aB01 += shfl_xor_h2(aB01, 8);
        aB23 += shfl_xor_h2(aB23, 8);
        lB += __shfl_xor(lB, 16);  lB += __shfl_xor(lB, 32);

        const float invA = (endA > beginA) ? (1.0f / lA) : 0.0f;
        const float invB = (endB > beginB) ? (1.0f / lB) : 0.0f;
        h2 ivA; ivA.x = (_Float16)invA; ivA.y = ivA.x;
        h2 ivB; ivB.x = (_Float16)invB; ivB.y = ivB.x;
        aA01 *= ivA;  aA23 *= ivA;
        aB01 *= ivB;  aB23 *= ivB;

        if ((g & 1) == 0) {                  // even groups hold pair sums
            const int p   = g >> 1;
            const int row = w * 4 + ia;
            int off = row * 68 + p * 16 + c * 2;   // uint32 units
            part32[off]     = as_u32(aA01);
            part32[off + 1] = as_u32(aA23);
            off += 68;
            part32[off]     = as_u32(aB01);
            part32[off + 1] = as_u32(aB23);
        }
    }

    __syncthreads();

    // wave 0: projection + partial-group reduction for the block's 16 nodes
    if (w == 0) {
        const int quad = lane >> 4;   // 0..3
        const int col  = lane & 15;

        union BF { h8 v; _Float16 u[8]; };
        BF bf0, bf1;
#pragma unroll
        for (int j2 = 0; j2 < 8; ++j2) {
            bf0.u[j2] = (_Float16)Wo[(quad * 8 + j2) * OUT_DIM + col];
            bf1.u[j2] = (_Float16)Wo[(quad * 8 + j2) * OUT_DIM + 16 + col];
        }
        const float bias0 = bo[col];
        const float bias1 = bo[16 + col];

        union AF { uint4 u; h8 v; };
        f32x4 C0 = {bias0, bias0, bias0, bias0};
        f32x4 C1 = {bias1, bias1, bias1, bias1};
#pragma unroll
        for (int cc = 0; cc < 4; ++cc) {
            AF a;
            a.u = s_part[col * 17 + cc * 4 + quad];      // ds_read_b128
            C0 = __builtin_amdgcn_mfma_f32_16x16x32_f16(a.v, bf0.v, C0, 0, 0, 0);
            C1 = __builtin_amdgcn_mfma_f32_16x16x32_f16(a.v, bf1.v, C1, 0, 0, 0);
        }
        // C/D layout: col = lane&15, row = quad*4 + reg (verified mapping)
#pragma unroll
        for (int r = 0; r < 4; ++r) {
            const int n = n_blk + quad * 4 + r;
            if (n < N) {
                out[n * OUT_DIM + col]      = C0[r];
                out[n * OUT_DIM + 16 + col] = C1[r];
            }
        }
    }
}

// ---- fallback (R4-proven fp32 path, used only if ws too small for KV) ----
__global__ __launch_bounds__(256) void gat_node_f32_kernel(
    const float* __restrict__ X, const float* __restrict__ Km,
    const float* __restrict__ Vm, const float* __restrict__ Wo,
    const float* __restrict__ bo, const int* __restrict__ src,
    const int* __restrict__ row_ptr, float* __restrict__ out, int N) {
    const int tid  = threadIdx.x;
    const int wave = tid >> 6;
    const int lane = tid & 63;
    const int g    = lane >> 3;
    const int c    = lane & 7;
    const int j    = lane & 31;
    const int half = lane >> 5;
    const int n = blockIdx.x * 4 + wave;
    if (n >= N) return;
    const int begin = row_ptr[n];
    const int end   = row_ptr[n + 1];
    const float4* X4 = (const float4*)X;
    const float4* K4 = (const float4*)Km;
    const float4* V4 = (const float4*)Vm;
    const float4 q4 = X4[n * 8 + c];
    float  l   = 0.0f;
    float4 acc = make_float4(0.0f, 0.0f, 0.0f, 0.0f);
    for (int e0 = begin; e0 < end; e0 += 16) {
        const int  ea = e0 + g;
        const int  eb = ea + 8;
        const bool va = ea < end;
        const bool vb = eb < end;
        const int sa = src[min(ea, end - 1)];
        const int sb = src[min(eb, end - 1)];
        const float4 ka  = K4[sa * 8 + c];
        const float4 kb  = K4[sb * 8 + c];
        const float4 vva = V4[sa * 8 + c];
        const float4 vvb = V4[sb * 8 + c];
        float pa = fmaf(ka.x, q4.x, fmaf(ka.y, q4.y, fmaf(ka.z, q4.z, ka.w * q4.w)));
        float pb = fmaf(kb.x, q4.x, fmaf(kb.y, q4.y, fmaf(kb.z, q4.z, kb.w * q4.w)));
        pa += __shfl_xor(pa, 1);  pb += __shfl_xor(pb, 1);
        pa += __shfl_xor(pa, 2);  pb += __shfl_xor(pb, 2);
        pa += __shfl_xor(pa, 4);  pb += __shfl_xor(pb, 4);
        const float wa = va ? __expf(pa * 0.03125f) : 0.0f;
        const float wb = vb ? __expf(pb * 0.03125f) : 0.0f;
        l += wa + wb;
        acc.x = fmaf(wa, vva.x, acc.x);  acc.y = fmaf(wa, vva.y, acc.y);
        acc.z = fmaf(wa, vva.z, acc.z);  acc.w = fmaf(wa, vva.w, acc.w);
        acc.x = fmaf(wb, vvb.x, acc.x);  acc.y = fmaf(wb, vvb.y, acc.y);
        acc.z = fmaf(wb, vvb.z, acc.z);  acc.w = fmaf(wb, vvb.w, acc.w);
    }
#pragma unroll
    for (int m = 8; m <= 32; m <<= 1) {
        l     += __shfl_xor(l, m);
        acc.x += __shfl_xor(acc.x, m);
        acc.y += __shfl_xor(acc.y, m);
        acc.z += __shfl_xor(acc.z, m);
        acc.w += __shfl_xor(acc.w, m);
    }
    const float inv = (end > begin) ? (1.0f / l) : 0.0f;
    float ag[4] = {acc.x, acc.y, acc.z, acc.w};
    float s = 0.0f;
#pragma unroll
    for (int k = 0; k < 32; ++k) {
        const float a = __int_as_float(
            __builtin_amdgcn_readlane(__float_as_int(ag[k & 3]), k >> 2));
        s = fmaf(a, Wo[k * OUT_DIM + j], s);
    }
    if (half == 0) {
        out[n * OUT_DIM + j] = fmaf(s, inv, bo[j]);
    }
}

extern "C" void kernel_launch(void* const* d_in, const int* in_sizes, int n_in,
                              void* d_out, int out_size, void* d_ws, size_t ws_size,
                              hipStream_t stream) {
    const float* X  = (const float*)d_in[0];
    const float* Km = (const float*)d_in[1];
    const float* Vm = (const float*)d_in[2];
    const float* Wo = (const float*)d_in[3];
    const float* bo = (const float*)d_in[4];
    const int* src  = (const int*)d_in[5];
    const int* dst  = (const int*)d_in[6];

    const int N = in_sizes[0] / DK;
    const int E = in_sizes[5];

    int* row_ptr = (int*)d_ws;                              // (N+1) ints
    const size_t kv_off = (((size_t)(N + 1) * 4) + 127) & ~(size_t)127;
    unsigned* KV = (unsigned*)((char*)d_ws + kv_off);       // N*DK uint32
    const size_t need = kv_off + (size_t)N * DK * 4;
    float* out = (float*)d_out;

    const int tb = 256;

    if (ws_size >= need) {
        const int total  = N * DK;
        const int prep_n = (E > total) ? E : total;
        prep_kernel<<<(prep_n + tb - 1) / tb, tb, 0, stream>>>(dst, Km, Vm, E, N,
                                                               row_ptr, KV);
        const int grid = (N + 15) / 16;     // 16 nodes per block, 4 per wave
        gat_fused_kernel<<<grid, 256, 0, stream>>>(X, (const uint4*)KV, Wo, bo,
                                                   src, row_ptr, out, N);
    } else {
        build_row_ptr_kernel<<<(E + tb - 1) / tb, tb, 0, stream>>>(dst, E, N, row_ptr);
        const int grid = (N + 3) / 4;
        gat_node_f32_kernel<<<grid, 256, 0, stream>>>(X, Km, Vm, Wo, bo,
                                                      src, row_ptr, out, N);
    }
}